// Round 1
// baseline (201.121 us; speedup 1.0000x reference)
//
#include <hip/hip_runtime.h>

// Problem constants
#define Bq 64
#define Sq 512
#define Hq 768
#define Tq 16
#define Vq 30522

// ---------- cross-lane helpers ----------
__device__ __forceinline__ float bperm_f(float v, int byteidx) {
    return __int_as_float(__builtin_amdgcn_ds_bpermute(byteidx, __float_as_int(v)));
}
__device__ __forceinline__ int bperm_i(int v, int byteidx) {
    return __builtin_amdgcn_ds_bpermute(byteidx, v);
}
template <int CTRL>
__device__ __forceinline__ float dpp_f(float v) {
    return __int_as_float(__builtin_amdgcn_mov_dpp(__float_as_int(v), CTRL, 0xF, 0xF, true));
}
template <int CTRL>
__device__ __forceinline__ int dpp_i(int v) {
    return __builtin_amdgcn_mov_dpp(v, CTRL, 0xF, 0xF, true);
}
// quad_perm xor1 = [1,0,3,2] -> 0xB1 ; xor2 = [2,3,0,1] -> 0x4E

// ---------- K0: table_logits[v][t] = emb_table[v] . W[:,t] + b[t] ----------
// block 256 threads (4 waves), 64 vocab rows / block, H split in 4 chunks of 192.
// LDS tile padded to 196 floats/row: compute-read is quad-broadcast, 2-way max (free).
__global__ __launch_bounds__(256) void k_table(const float* __restrict__ emb,
                                               const float* __restrict__ W,
                                               const float* __restrict__ bias,
                                               float* __restrict__ table,
                                               float* __restrict__ out) {
    if (blockIdx.x == 0 && threadIdx.x == 0) out[1] = 0.0f;  // init 'correct' accumulator
    __shared__ float a[64][196];
    const int tid   = threadIdx.x;
    const int v0    = blockIdx.x * 64;
    const int r_loc = ((tid >> 6) << 4) | ((tid >> 2) & 15);  // row 0..63 within tile
    const int t0    = (tid & 3) << 2;                          // tag group {0,4,8,12}

    float4 acc = *reinterpret_cast<const float4*>(bias + t0);

    for (int c = 0; c < 4; ++c) {
        const int h0c = c * 192;
        // stage 64 rows x 192 floats (coalesced float4, guarded at vocab tail)
        #pragma unroll
        for (int k = 0; k < 12; ++k) {
            int e4 = tid + (k << 8);        // 0..3071 float4 slots
            int rr = e4 / 48;
            int cc = e4 - rr * 48;
            int v  = v0 + rr;
            float4 val = make_float4(0.f, 0.f, 0.f, 0.f);
            if (v < Vq)
                val = *reinterpret_cast<const float4*>(emb + (size_t)v * Hq + h0c + (cc << 2));
            *reinterpret_cast<float4*>(&a[rr][cc << 2]) = val;
        }
        __syncthreads();
        #pragma unroll 8
        for (int h = 0; h < 192; h += 4) {
            float4 av = *reinterpret_cast<const float4*>(&a[r_loc][h]);
            const float* wp = W + (size_t)(h0c + h) * Tq + t0;
            float4 w0 = *reinterpret_cast<const float4*>(wp);
            float4 w1 = *reinterpret_cast<const float4*>(wp + Tq);
            float4 w2 = *reinterpret_cast<const float4*>(wp + 2 * Tq);
            float4 w3 = *reinterpret_cast<const float4*>(wp + 3 * Tq);
            acc.x = fmaf(av.x, w0.x, acc.x);
            acc.y = fmaf(av.x, w0.y, acc.y);
            acc.z = fmaf(av.x, w0.z, acc.z);
            acc.w = fmaf(av.x, w0.w, acc.w);
            acc.x = fmaf(av.y, w1.x, acc.x);
            acc.y = fmaf(av.y, w1.y, acc.y);
            acc.z = fmaf(av.y, w1.z, acc.z);
            acc.w = fmaf(av.y, w1.w, acc.w);
            acc.x = fmaf(av.z, w2.x, acc.x);
            acc.y = fmaf(av.z, w2.y, acc.y);
            acc.z = fmaf(av.z, w2.z, acc.z);
            acc.w = fmaf(av.z, w2.w, acc.w);
            acc.x = fmaf(av.w, w3.x, acc.x);
            acc.y = fmaf(av.w, w3.y, acc.y);
            acc.z = fmaf(av.w, w3.z, acc.z);
            acc.w = fmaf(av.w, w3.w, acc.w);
        }
        __syncthreads();
    }
    int v = v0 + r_loc;
    if (v < Vq) *reinterpret_cast<float4*>(table + (size_t)v * Tq + t0) = acc;
}

// ---------- K1: fused CRF scans. grid=128, block=64 (1 wave). ----------
// blocks 0..63  : denominator (linear-domain forward) + numerator  -> nd[b] = num - den
// blocks 64..127: viterbi forward + backtrack + pred/label/correct outputs
__global__ __launch_bounds__(64) void k_scan(const int* __restrict__ src,
                                             const int* __restrict__ label,
                                             const int* __restrict__ pmask,
                                             const float* __restrict__ table,
                                             const float* __restrict__ start_t,
                                             const float* __restrict__ end_t,
                                             const float* __restrict__ trans,
                                             float* __restrict__ nd,
                                             float* __restrict__ out) {
    __shared__ float em[Sq * Tq];                 // 32 KB emissions for this batch
    __shared__ unsigned char hist8[(Sq - 1) * Tq];  // viterbi argmax history
    __shared__ int srcl[Sq];
    __shared__ int labl[Sq];
    __shared__ int predi[Sq];

    const int lane = threadIdx.x;
    const int b    = blockIdx.x & 63;
    const bool vit = blockIdx.x >= 64;

    // stage src & label rows
    #pragma unroll
    for (int k = 0; k < 8; ++k) {
        int t = lane + (k << 6);
        srcl[t] = src[b * Sq + t];
        labl[t] = label[b * Sq + t];
    }
    __syncthreads();
    // gather emissions: em[t*16+j] = table_logits[src[t]][j]
    #pragma unroll 4
    for (int k = 0; k < 128; ++k) {
        int idx = lane + (k << 6);
        em[idx] = table[(size_t)srcl[idx >> 4] * Tq + (idx & 15)];
    }
    __syncthreads();

    const int j = lane >> 2;   // state 0..15 (quad index)
    const int g = lane & 3;    // prev-state group: i in {4g..4g+3}
    // bpermute byte indices: p[i] lives in lanes 4i..4i+3 -> byte 16*i
    const int bidx0 = (g << 6);
    const int bidx1 = (g << 6) + 16;
    const int bidx2 = (g << 6) + 32;
    const int bidx3 = (g << 6) + 48;

    if (!vit) {
        // ================= denominator: linear-domain forward =================
        // p'[j] = (sum_i p[i]*exp(trans[i][j])) * exp(em_t[j]) / 16  (exact /16 each step)
        float E0 = __expf(trans[(4 * g + 0) * Tq + j]);
        float E1 = __expf(trans[(4 * g + 1) * Tq + j]);
        float E2 = __expf(trans[(4 * g + 2) * Tq + j]);
        float E3 = __expf(trans[(4 * g + 3) * Tq + j]);
        float p = __expf(start_t[j] + em[j]);  // alpha0, c=0
        float emA = em[Tq + j], emB = em[2 * Tq + j], emC = em[3 * Tq + j];
        for (int t = 1; t < Sq; ++t) {
            float FF = __expf(emA) * 0.0625f;  // exp(em_t)/16, off critical chain
            emA = emB; emB = emC;
            int tn = t + 3; if (tn > Sq - 1) tn = Sq - 1;
            emC = em[tn * Tq + j];
            float p0 = bperm_f(p, bidx0);
            float p1 = bperm_f(p, bidx1);
            float p2 = bperm_f(p, bidx2);
            float p3 = bperm_f(p, bidx3);
            float s = (p0 * E0 + p1 * E1) + (p2 * E2 + p3 * E3);
            s += dpp_f<0xB1>(s);   // quad xor1
            s += dpp_f<0x4E>(s);   // quad xor2 -> full 16-term sum, quad-replicated
            p = s * FF;
        }
        float val = p * __expf(end_t[j]);
        #pragma unroll
        for (int off = 1; off < 64; off <<= 1) val += __shfl_xor(val, off);
        // sum over 64 lanes = 4 * sum_j ; den = 511*ln(16) + ln(sum_j p_j*exp(end_j))
        float den = (float)(511.0 * 2.7725887222397811) + __logf(val * 0.25f);

        // ================= numerator (parallel over t) =================
        float numv = 0.0f;
        int sl = 0;
        #pragma unroll
        for (int k = 0; k < 8; ++k) {
            int t = lane + (k << 6);
            int tag = labl[t];
            int m = pmask[b * Sq + t];
            sl += m;
            if (t == 0) {
                numv += start_t[tag] + em[tag];
            } else {
                int tp = labl[t - 1];
                numv += (float)m * (trans[tp * Tq + tag] + em[t * Tq + tag]);
            }
        }
        #pragma unroll
        for (int off = 1; off < 64; off <<= 1) {
            numv += __shfl_xor(numv, off);
            sl += __shfl_xor(sl, off);
        }
        if (lane == 0) {
            int last = labl[sl - 1];
            nd[b] = (numv + end_t[last]) - den;
        }
    } else {
        // ================= viterbi forward =================
        float T0 = trans[(4 * g + 0) * Tq + j];
        float T1 = trans[(4 * g + 1) * Tq + j];
        float T2 = trans[(4 * g + 2) * Tq + j];
        float T3 = trans[(4 * g + 3) * Tq + j];
        const int i0 = 4 * g, i1 = 4 * g + 1, i2 = 4 * g + 2, i3 = 4 * g + 3;
        float sc = start_t[j] + em[j];
        float emA = em[Tq + j], emB = em[2 * Tq + j], emC = em[3 * Tq + j];
        for (int t = 1; t < Sq; ++t) {
            float emv = emA;
            emA = emB; emB = emC;
            int tn = t + 3; if (tn > Sq - 1) tn = Sq - 1;
            emC = em[tn * Tq + j];
            float v0 = bperm_f(sc, bidx0) + T0;
            float v1 = bperm_f(sc, bidx1) + T1;
            float v2 = bperm_f(sc, bidx2) + T2;
            float v3 = bperm_f(sc, bidx3) + T3;
            // local argmax over 4 (ties -> lowest index, matching jnp.argmax)
            float mv01 = v1 > v0 ? v1 : v0;  int mi01 = v1 > v0 ? i1 : i0;
            float mv23 = v3 > v2 ? v3 : v2;  int mi23 = v3 > v2 ? i3 : i2;
            float mv = mv23 > mv01 ? mv23 : mv01;
            int   mi = mv23 > mv01 ? mi23 : mi01;
            {
                float ov = dpp_f<0xB1>(mv); int oi = dpp_i<0xB1>(mi);
                bool take = (ov > mv) || (ov == mv && oi < mi);
                mv = take ? ov : mv; mi = take ? oi : mi;
            }
            {
                float ov = dpp_f<0x4E>(mv); int oi = dpp_i<0x4E>(mi);
                bool take = (ov > mv) || (ov == mv && oi < mi);
                mv = take ? ov : mv; mi = take ? oi : mi;
            }
            sc = mv + emv;
            if (g == 0) hist8[(t - 1) * Tq + j] = (unsigned char)mi;
        }
        __syncthreads();
        // final argmax over states j (quad-replicated values; ties -> lowest j)
        float fv = sc + end_t[j];
        int fi = j;
        #pragma unroll
        for (int off = 4; off < 64; off <<= 1) {
            float ov = __shfl_xor(fv, off);
            int oi = __shfl_xor(fi, off);
            bool take = (ov > fv) || (ov == fv && oi < fi);
            fv = take ? ov : fv; fi = take ? oi : fi;
        }
        // ================= backtrack (register-staged bpermute chains) =================
        int cur = fi;
        if (lane == 0) predi[Sq - 1] = cur;
        const int col = lane & 15;
        for (int cb = 63; cb >= 0; --cb) {
            int hv[8];
            #pragma unroll
            for (int k = 0; k < 8; ++k) {
                int r = cb * 8 + k; if (r > Sq - 2) r = Sq - 2;
                hv[k] = hist8[r * Tq + col];
            }
            #pragma unroll
            for (int k = 7; k >= 0; --k) {
                int r = cb * 8 + k;
                if (r <= Sq - 2) {
                    cur = bperm_i(hv[k], cur << 2);  // pulls hist[r][cur]
                    if (lane == 0) predi[r] = cur;
                }
            }
        }
        __syncthreads();
        // ================= outputs =================
        int cnt = 0;
        #pragma unroll
        for (int k = 0; k < 8; ++k) {
            int s_ = lane + (k << 6);
            int lab = labl[s_];
            int pr = predi[s_];
            int mpr = lab > 0 ? pr : 0;
            out[2 + b * Sq + s_] = (float)mpr;
            out[2 + Bq * Sq + b * Sq + s_] = (float)lab;
            cnt += (mpr == lab) ? 1 : 0;
        }
        #pragma unroll
        for (int off = 1; off < 64; off <<= 1) cnt += __shfl_xor(cnt, off);
        if (lane == 0) atomicAdd(out + 1, (float)cnt);
    }
}

// ---------- K2: loss = -(sum_b nd[b]) / B ----------
__global__ __launch_bounds__(64) void k_final(const float* __restrict__ nd,
                                              float* __restrict__ out) {
    float v = nd[threadIdx.x];
    #pragma unroll
    for (int off = 1; off < 64; off <<= 1) v += __shfl_xor(v, off);
    if (threadIdx.x == 0) out[0] = -v * (1.0f / (float)Bq);
}

extern "C" void kernel_launch(void* const* d_in, const int* in_sizes, int n_in,
                              void* d_out, int out_size, void* d_ws, size_t ws_size,
                              hipStream_t stream) {
    const int*   src   = (const int*)d_in[0];
    const int*   label = (const int*)d_in[1];
    const int*   pmask = (const int*)d_in[2];
    const float* emb   = (const float*)d_in[3];
    const float* W     = (const float*)d_in[4];
    const float* bias  = (const float*)d_in[5];
    const float* st    = (const float*)d_in[6];
    const float* en    = (const float*)d_in[7];
    const float* tr    = (const float*)d_in[8];
    float* out = (float*)d_out;

    float* table = (float*)d_ws;          // V*T floats = 1.95 MB
    float* nd    = table + (size_t)Vq * Tq;  // 64 floats

    const int nblk = (Vq + 63) / 64;      // 477
    k_table<<<nblk, 256, 0, stream>>>(emb, W, bias, table, out);
    k_scan<<<128, 64, 0, stream>>>(src, label, pmask, table, st, en, tr, nd, out);
    k_final<<<1, 64, 0, stream>>>(nd, out);
}

// Round 2
// 157.123 us; speedup vs baseline: 1.2800x; 1.2800x over previous
//
#include <hip/hip_runtime.h>

#define Bq 64
#define Sq 512
#define Hq 768
#define Tq 16
#define Vq 30522

typedef unsigned int u32;
typedef unsigned long long u64;

// ---------- cross-lane helpers ----------
__device__ __forceinline__ float bperm_f(float v, int byteidx) {
    return __int_as_float(__builtin_amdgcn_ds_bpermute(byteidx, __float_as_int(v)));
}
template <int CTRL>
__device__ __forceinline__ int dpp_i(int v) {
    return __builtin_amdgcn_mov_dpp(v, CTRL, 0xF, 0xF, true);
}
template <int CTRL>
__device__ __forceinline__ u32 dpp_u(u32 v) { return (u32)dpp_i<CTRL>((int)v); }
template <int CTRL>
__device__ __forceinline__ float dpp_f(float v) {
    return __int_as_float(dpp_i<CTRL>(__float_as_int(v)));
}

#define QX1 0xB1   // quad_perm xor 1
#define QX2 0x4E   // quad_perm xor 2
#define RR4  0x124 // row_ror:4
#define RR8  0x128 // row_ror:8
#define RR12 0x12C // row_ror:12

#if defined(__gfx950__) && __has_builtin(__builtin_amdgcn_permlane32_swap) && __has_builtin(__builtin_amdgcn_permlane16_swap)
#define HAVE_PL 1
#else
#define HAVE_PL 0
#endif

#if HAVE_PL
// x from lane (l ^ 32): xor-combine is correct under either role-assignment of
// the pair-swap instruction (pure bit movement, so a^b^x reconstructs).
__device__ __forceinline__ u32 xlane32(u32 x) {
    auto r = __builtin_amdgcn_permlane32_swap((int)x, (int)x, false, false);
    return ((u32)r[0]) ^ ((u32)r[1]) ^ x;
}
__device__ __forceinline__ u32 xlane16(u32 x) {
    auto r = __builtin_amdgcn_permlane16_swap((int)x, (int)x, false, false);
    return ((u32)r[0]) ^ ((u32)r[1]) ^ x;
}
// digit-swap gather: lane (a,b,c) receives p[4c + k_r] in q_r (k-map decoded by probe)
__device__ __forceinline__ void gather4(u32 x, bool swA, bool swB,
                                        u32& q0, u32& q1, u32& q2, u32& q3) {
    u32 t  = xlane32(x);        // l ^ 32
    u32 y  = dpp_u<QX2>(t);     // l ^ 34
    u32 z  = swA ? y : x;       // swap bits 5<->1 where they differ
    u32 t2 = xlane16(z);        // l ^ 16
    u32 y2 = dpp_u<QX1>(t2);    // l ^ 17
    q0 = swB ? y2 : z;          // swap bits 4<->0
    q1 = dpp_u<RR4>(q0);
    q2 = dpp_u<RR8>(q0);
    q3 = dpp_u<RR12>(q0);
}
#endif

__device__ __forceinline__ u32 packnib(u32 d) {     // bytes (<16) -> 16-bit nibble pack
    u32 y = d | (d >> 4);
    y &= 0x00FF00FFu;
    y = (y | (y >> 8)) & 0xFFFFu;
    return y;
}
__device__ __forceinline__ u32 nib64(u64 f, u32 s) {
    return ((u32)(f >> (s << 2))) & 15u;
}

// ---------- K0: table_logits[v][t] = emb[v].W[:,t] + b[t]  (no LDS, scalar W) ----------
__global__ __launch_bounds__(64) void k_table(const float* __restrict__ emb,
                                              const float* __restrict__ W,
                                              const float* __restrict__ bias,
                                              float* __restrict__ table,
                                              float* __restrict__ out) {
    if (blockIdx.x == 0 && threadIdx.x == 0) out[1] = 0.0f;
    const int lane = threadIdx.x;
    const int v = blockIdx.x * 64 + lane;
    const int vc = v < Vq ? v : Vq - 1;
    const float* arow = emb + (size_t)vc * Hq;

    float acc[16];
    #pragma unroll
    for (int t = 0; t < 16; ++t) acc[t] = bias[t];

    float4 buf[8];
    #pragma unroll
    for (int i = 0; i < 8; ++i) buf[i] = *reinterpret_cast<const float4*>(arow + i * 4);

    for (int h0 = 0; h0 < Hq; h0 += 32) {
        float4 nxt[8];
        const bool more = (h0 + 32) < Hq;
        if (more) {
            #pragma unroll
            for (int i = 0; i < 8; ++i)
                nxt[i] = *reinterpret_cast<const float4*>(arow + h0 + 32 + i * 4);
        }
        #pragma unroll
        for (int i = 0; i < 8; ++i) {
            const float* wb = W + (size_t)(h0 + i * 4) * Tq;   // wave-uniform -> s_load
            #pragma unroll
            for (int u = 0; u < 4; ++u) {
                float av = (u == 0) ? buf[i].x : (u == 1) ? buf[i].y : (u == 2) ? buf[i].z : buf[i].w;
                #pragma unroll
                for (int t = 0; t < 16; ++t)
                    acc[t] = fmaf(av, wb[u * Tq + t], acc[t]);
            }
        }
        if (more) {
            #pragma unroll
            for (int i = 0; i < 8; ++i) buf[i] = nxt[i];
        }
    }
    if (v < Vq) {
        #pragma unroll
        for (int c = 0; c < 4; ++c)
            *reinterpret_cast<float4*>(table + (size_t)v * Tq + c * 4) =
                make_float4(acc[c * 4], acc[c * 4 + 1], acc[c * 4 + 2], acc[c * 4 + 3]);
    }
}

// ---------- K1: fused CRF scans. grid=128, block=64 (1 wave). ----------
__global__ __launch_bounds__(64) void k_scan(const int* __restrict__ src,
                                             const int* __restrict__ label,
                                             const int* __restrict__ pmask,
                                             const float* __restrict__ table,
                                             const float* __restrict__ start_t,
                                             const float* __restrict__ end_t,
                                             const float* __restrict__ trans,
                                             float* __restrict__ nd,
                                             float* __restrict__ out) {
    __shared__ float em[Sq * Tq];
    __shared__ __align__(16) unsigned char hist8[Sq * Tq]; // rows 0..510 + row 511 = identity
    __shared__ int srcl[Sq];
    __shared__ int labl[Sq];
    __shared__ __align__(8) unsigned char predi8[Sq];

    const int lane = threadIdx.x;
    const int b = blockIdx.x & 63;
    const bool vit = blockIdx.x >= 64;

    #pragma unroll
    for (int k = 0; k < 8; ++k) {
        int t = lane + (k << 6);
        srcl[t] = src[b * Sq + t];
        labl[t] = label[b * Sq + t];
    }
    __syncthreads();
    #pragma unroll 4
    for (int k = 0; k < 128; ++k) {
        int idx = lane + (k << 6);
        em[idx] = table[(size_t)srcl[idx >> 4] * Tq + (idx & 15)];
    }
    __syncthreads();

    const int j = lane >> 2;   // target state
    const int g = lane & 3;    // prev-state group

    // ---- probe the fast gather network; fall back to bpermute if semantics differ ----
    const bool swA = (((lane >> 5) ^ (lane >> 1)) & 1) != 0;
    const bool swB = (((lane >> 4) ^ lane) & 1) != 0;
    int k0 = 0, k1 = 1, k2 = 2, k3 = 3;
    bool fastok = false;
#if HAVE_PL
    {
        u32 q0, q1, q2, q3;
        gather4((u32)j, swA, swB, q0, q1, q2, q3);
        bool ok = ((q0 >> 2) == (u32)g) && ((q1 >> 2) == (u32)g) &&
                  ((q2 >> 2) == (u32)g) && ((q3 >> 2) == (u32)g);
        u32 cov = (1u << (q0 & 3)) | (1u << (q1 & 3)) | (1u << (q2 & 3)) | (1u << (q3 & 3));
        ok = ok && (cov == 15u);
        fastok = (__all(ok ? 1 : 0) != 0);
        if (fastok) { k0 = (int)(q0 & 3); k1 = (int)(q1 & 3); k2 = (int)(q2 & 3); k3 = (int)(q3 & 3); }
    }
#endif
    const int bidx0 = (g << 6), bidx1 = (g << 6) + 16, bidx2 = (g << 6) + 32, bidx3 = (g << 6) + 48;

    if (!vit) {
        // ================= denominator: linear-domain forward =================
        float E0 = __expf(trans[(4 * g + k0) * Tq + j]);
        float E1 = __expf(trans[(4 * g + k1) * Tq + j]);
        float E2 = __expf(trans[(4 * g + k2) * Tq + j]);
        float E3 = __expf(trans[(4 * g + k3) * Tq + j]);
        float p = __expf(start_t[j] + em[j]);
        float emA = em[Tq + j], emB = em[2 * Tq + j], emC = em[3 * Tq + j];
#if HAVE_PL
        if (fastok) {
            for (int t = 1; t < Sq; ++t) {
                float FF = __expf(emA) * 0.0625f;
                emA = emB; emB = emC;
                int tn = t + 3; if (tn > Sq - 1) tn = Sq - 1;
                emC = em[tn * Tq + j];
                u32 qa, qb, qc, qd;
                gather4(__float_as_uint(p), swA, swB, qa, qb, qc, qd);
                float s = (__uint_as_float(qa) * E0 + __uint_as_float(qb) * E1)
                        + (__uint_as_float(qc) * E2 + __uint_as_float(qd) * E3);
                s += dpp_f<QX1>(s);
                s += dpp_f<QX2>(s);
                p = s * FF;
            }
        } else
#endif
        {
            for (int t = 1; t < Sq; ++t) {
                float FF = __expf(emA) * 0.0625f;
                emA = emB; emB = emC;
                int tn = t + 3; if (tn > Sq - 1) tn = Sq - 1;
                emC = em[tn * Tq + j];
                float p0 = bperm_f(p, bidx0);
                float p1 = bperm_f(p, bidx1);
                float p2 = bperm_f(p, bidx2);
                float p3 = bperm_f(p, bidx3);
                float s = (p0 * E0 + p1 * E1) + (p2 * E2 + p3 * E3);
                s += dpp_f<QX1>(s);
                s += dpp_f<QX2>(s);
                p = s * FF;
            }
        }
        float val = p * __expf(end_t[j]);
        #pragma unroll
        for (int off = 1; off < 64; off <<= 1) val += __shfl_xor(val, off);
        float den = (float)(511.0 * 2.7725887222397811) + __logf(val * 0.25f);

        // ================= numerator =================
        float numv = 0.0f;
        int sl = 0;
        #pragma unroll
        for (int k = 0; k < 8; ++k) {
            int t = lane + (k << 6);
            int tag = labl[t];
            int m = pmask[b * Sq + t];
            sl += m;
            if (t == 0) {
                numv += start_t[tag] + em[tag];
            } else {
                int tp = labl[t - 1];
                numv += (float)m * (trans[tp * Tq + tag] + em[t * Tq + tag]);
            }
        }
        #pragma unroll
        for (int off = 1; off < 64; off <<= 1) {
            numv += __shfl_xor(numv, off);
            sl += __shfl_xor(sl, off);
        }
        if (lane == 0) {
            int last = labl[sl - 1];
            nd[b] = (numv + end_t[last]) - den;
        }
    } else {
        // ================= viterbi forward =================
        float T0 = trans[(4 * g + k0) * Tq + j];
        float T1 = trans[(4 * g + k1) * Tq + j];
        float T2 = trans[(4 * g + k2) * Tq + j];
        float T3 = trans[(4 * g + k3) * Tq + j];
        const int i0 = 4 * g + k0, i1 = 4 * g + k1, i2 = 4 * g + k2, i3 = 4 * g + k3;
        float sc = start_t[j] + em[j];
        float emA = em[Tq + j], emB = em[2 * Tq + j], emC = em[3 * Tq + j];
#if HAVE_PL
        if (fastok) {
            for (int t = 1; t < Sq; ++t) {
                float emv = emA;
                emA = emB; emB = emC;
                int tn = t + 3; if (tn > Sq - 1) tn = Sq - 1;
                emC = em[tn * Tq + j];
                u32 qa, qb, qc, qd;
                gather4(__float_as_uint(sc), swA, swB, qa, qb, qc, qd);
                float v0 = __uint_as_float(qa) + T0;
                float v1 = __uint_as_float(qb) + T1;
                float v2 = __uint_as_float(qc) + T2;
                float v3 = __uint_as_float(qd) + T3;
                float ml = fmaxf(fmaxf(v0, v1), fmaxf(v2, v3));
                float m1 = fmaxf(ml, dpp_f<QX1>(ml));
                float mv = fmaxf(m1, dpp_f<QX2>(m1));
                sc = mv + emv;
                int c0 = (v0 == mv) ? i0 : 99;
                int c1 = (v1 == mv) ? i1 : 99;
                int c2 = (v2 == mv) ? i2 : 99;
                int c3 = (v3 == mv) ? i3 : 99;
                int li = min(min(c0, c1), min(c2, c3));
                li = min(li, dpp_i<QX1>(li));
                li = min(li, dpp_i<QX2>(li));
                if (g == 0) hist8[(t - 1) * Tq + j] = (unsigned char)li;
            }
        } else
#endif
        {
            for (int t = 1; t < Sq; ++t) {
                float emv = emA;
                emA = emB; emB = emC;
                int tn = t + 3; if (tn > Sq - 1) tn = Sq - 1;
                emC = em[tn * Tq + j];
                float v0 = bperm_f(sc, bidx0) + T0;
                float v1 = bperm_f(sc, bidx1) + T1;
                float v2 = bperm_f(sc, bidx2) + T2;
                float v3 = bperm_f(sc, bidx3) + T3;
                float ml = fmaxf(fmaxf(v0, v1), fmaxf(v2, v3));
                float m1 = fmaxf(ml, dpp_f<QX1>(ml));
                float mv = fmaxf(m1, dpp_f<QX2>(m1));
                sc = mv + emv;
                int c0 = (v0 == mv) ? i0 : 99;
                int c1 = (v1 == mv) ? i1 : 99;
                int c2 = (v2 == mv) ? i2 : 99;
                int c3 = (v3 == mv) ? i3 : 99;
                int li = min(min(c0, c1), min(c2, c3));
                li = min(li, dpp_i<QX1>(li));
                li = min(li, dpp_i<QX2>(li));
                if (g == 0) hist8[(t - 1) * Tq + j] = (unsigned char)li;
            }
        }
        // final argmax over states (ties -> lowest index)
        float fv = sc + end_t[j];
        int fi = j;
        #pragma unroll
        for (int off = 4; off < 64; off <<= 1) {
            float ov = __shfl_xor(fv, off);
            int oi = __shfl_xor(fi, off);
            bool take = (ov > fv) || (ov == fv && oi < fi);
            fv = take ? ov : fv;
            fi = take ? oi : fi;
        }
        // identity function as row 511 -> uniform 8-row chunks
        if (lane < 16) hist8[511 * Tq + lane] = (unsigned char)lane;
        __syncthreads();

        // ===== backtrack via exact function-composition scan =====
        // phase 1: lane c composes its 8 rows (nibble-packed functions)
        u64 rp[8];
        #pragma unroll
        for (int k = 0; k < 8; ++k) {
            uint4 rw = *reinterpret_cast<const uint4*>(&hist8[(lane * 8 + k) * Tq]);
            u32 lo = packnib(rw.x) | (packnib(rw.y) << 16);
            u32 hi = packnib(rw.z) | (packnib(rw.w) << 16);
            rp[k] = (u64)lo | ((u64)hi << 32);
        }
        u64 F = rp[7];
        #pragma unroll
        for (int k = 6; k >= 0; --k) {
            u64 nf = 0;
            #pragma unroll
            for (int e = 0; e < 16; ++e) {
                u32 s = (u32)(F >> (e * 4)) & 15u;
                nf |= ((u64)nib64(rp[k], s)) << (e * 4);
            }
            F = nf;
        }
        u32 Flo = (u32)F, Fhi = (u32)(F >> 32);

        // phase 2: sequential scalar scan over 64 chunk functions
        u32 pk[8] = {0, 0, 0, 0, 0, 0, 0, 0};
        u32 E = (u32)fi;
        #pragma unroll 64
        for (int c = 63; c >= 0; --c) {
            u64 Fc = ((u64)(u32)__builtin_amdgcn_readlane((int)Fhi, c) << 32)
                   | (u64)(u32)__builtin_amdgcn_readlane((int)Flo, c);
            pk[c >> 3] |= E << ((c & 7) * 4);   // record entry state E_c
            E = nib64(Fc, E);
        }

        // phase 3: parallel expansion; lane c emits predi[8c..8c+7]
        u32 a0 = (lane & 8) ? pk[1] : pk[0];
        u32 a1 = (lane & 8) ? pk[3] : pk[2];
        u32 a2 = (lane & 8) ? pk[5] : pk[4];
        u32 a3 = (lane & 8) ? pk[7] : pk[6];
        u32 b0 = (lane & 16) ? a1 : a0;
        u32 b1 = (lane & 16) ? a3 : a2;
        u32 c0s = (lane & 32) ? b1 : b0;
        u32 cur = (c0s >> ((lane & 7) * 4)) & 15u;
        u32 w0 = 0, w1 = 0;
        #pragma unroll
        for (int k = 7; k >= 0; --k) {
            cur = nib64(rp[k], cur);
            if (k >= 4) w1 |= cur << ((k - 4) * 8);
            else        w0 |= cur << (k * 8);
        }
        *reinterpret_cast<uint2*>(&predi8[lane * 8]) = make_uint2(w0, w1);
        __syncthreads();

        // ================= outputs =================
        int cnt = 0;
        #pragma unroll
        for (int k = 0; k < 8; ++k) {
            int s_ = lane + (k << 6);
            int lab = labl[s_];
            int pr = (int)predi8[s_];
            int mpr = lab > 0 ? pr : 0;
            out[2 + b * Sq + s_] = (float)mpr;
            out[2 + Bq * Sq + b * Sq + s_] = (float)lab;
            cnt += (mpr == lab) ? 1 : 0;
        }
        #pragma unroll
        for (int off = 1; off < 64; off <<= 1) cnt += __shfl_xor(cnt, off);
        if (lane == 0) atomicAdd(out + 1, (float)cnt);
    }
}

// ---------- K2: loss = -(sum_b nd[b]) / B ----------
__global__ __launch_bounds__(64) void k_final(const float* __restrict__ nd,
                                              float* __restrict__ out) {
    float v = nd[threadIdx.x];
    #pragma unroll
    for (int off = 1; off < 64; off <<= 1) v += __shfl_xor(v, off);
    if (threadIdx.x == 0) out[0] = -v * (1.0f / (float)Bq);
}

extern "C" void kernel_launch(void* const* d_in, const int* in_sizes, int n_in,
                              void* d_out, int out_size, void* d_ws, size_t ws_size,
                              hipStream_t stream) {
    const int*   src   = (const int*)d_in[0];
    const int*   label = (const int*)d_in[1];
    const int*   pmask = (const int*)d_in[2];
    const float* emb   = (const float*)d_in[3];
    const float* W     = (const float*)d_in[4];
    const float* bias  = (const float*)d_in[5];
    const float* st    = (const float*)d_in[6];
    const float* en    = (const float*)d_in[7];
    const float* tr    = (const float*)d_in[8];
    float* out = (float*)d_out;

    float* table = (float*)d_ws;              // V*T floats = 1.95 MB
    float* nd    = table + (size_t)Vq * Tq;   // 64 floats

    const int nblk = (Vq + 63) / 64;          // 477
    k_table<<<nblk, 64, 0, stream>>>(emb, W, bias, table, out);
    k_scan<<<128, 64, 0, stream>>>(src, label, pmask, table, st, en, tr, nd, out);
    k_final<<<1, 64, 0, stream>>>(nd, out);
}

// Round 3
// 156.925 us; speedup vs baseline: 1.2816x; 1.0013x over previous
//
#include <hip/hip_runtime.h>

#define Bq 64
#define Sq 512
#define Hq 768
#define Tq 16
#define Vq 30522

typedef unsigned int u32;
typedef unsigned long long u64;

// ---------- cross-lane helpers ----------
__device__ __forceinline__ float bperm_f(float v, int byteidx) {
    return __int_as_float(__builtin_amdgcn_ds_bpermute(byteidx, __float_as_int(v)));
}
template <int CTRL>
__device__ __forceinline__ int dpp_i(int v) {
    return __builtin_amdgcn_mov_dpp(v, CTRL, 0xF, 0xF, true);
}
template <int CTRL>
__device__ __forceinline__ u32 dpp_u(u32 v) { return (u32)dpp_i<CTRL>((int)v); }
template <int CTRL>
__device__ __forceinline__ float dpp_f(float v) {
    return __int_as_float(dpp_i<CTRL>(__float_as_int(v)));
}

#define QX1 0xB1   // quad_perm xor 1
#define QX2 0x4E   // quad_perm xor 2
#define RR4  0x124 // row_ror:4
#define RR8  0x128 // row_ror:8
#define RR12 0x12C // row_ror:12

#if defined(__gfx950__) && __has_builtin(__builtin_amdgcn_permlane32_swap) && __has_builtin(__builtin_amdgcn_permlane16_swap)
#define HAVE_PL 1
#else
#define HAVE_PL 0
#endif

#if HAVE_PL
// x from lane (l ^ 32): xor-combine is correct under either role-assignment of
// the pair-swap instruction (pure bit movement, so a^b^x reconstructs).
__device__ __forceinline__ u32 xlane32(u32 x) {
    auto r = __builtin_amdgcn_permlane32_swap((int)x, (int)x, false, false);
    return ((u32)r[0]) ^ ((u32)r[1]) ^ x;
}
__device__ __forceinline__ u32 xlane16(u32 x) {
    auto r = __builtin_amdgcn_permlane16_swap((int)x, (int)x, false, false);
    return ((u32)r[0]) ^ ((u32)r[1]) ^ x;
}
// digit-swap gather: lane (a,b,c) receives p[4c + k_r] in q_r (k-map decoded by probe)
__device__ __forceinline__ void gather4(u32 x, bool swA, bool swB,
                                        u32& q0, u32& q1, u32& q2, u32& q3) {
    u32 t  = xlane32(x);        // l ^ 32
    u32 y  = dpp_u<QX2>(t);     // l ^ 34
    u32 z  = swA ? y : x;       // swap bits 5<->1 where they differ
    u32 t2 = xlane16(z);        // l ^ 16
    u32 y2 = dpp_u<QX1>(t2);    // l ^ 17
    q0 = swB ? y2 : z;          // swap bits 4<->0
    q1 = dpp_u<RR4>(q0);
    q2 = dpp_u<RR8>(q0);
    q3 = dpp_u<RR12>(q0);
}
#endif

__device__ __forceinline__ u32 packnib(u32 d) {     // bytes (<16) -> 16-bit nibble pack
    u32 y = d | (d >> 4);
    y &= 0x00FF00FFu;
    y = (y | (y >> 8)) & 0xFFFFu;
    return y;
}
__device__ __forceinline__ u32 nib64(u64 f, u32 s) {
    return ((u32)(f >> (s << 2))) & 15u;
}

// ---------- K0: table_logits[v][t] = emb[v].W[:,t] + b[t]  (no LDS, scalar W) ----------
__global__ __launch_bounds__(64) void k_table(const float* __restrict__ emb,
                                              const float* __restrict__ W,
                                              const float* __restrict__ bias,
                                              float* __restrict__ table,
                                              float* __restrict__ out) {
    if (blockIdx.x == 0 && threadIdx.x == 0) out[1] = 0.0f;
    const int lane = threadIdx.x;
    const int v = blockIdx.x * 64 + lane;
    const int vc = v < Vq ? v : Vq - 1;
    const float* arow = emb + (size_t)vc * Hq;

    float acc[16];
    #pragma unroll
    for (int t = 0; t < 16; ++t) acc[t] = bias[t];

    float4 buf[8];
    #pragma unroll
    for (int i = 0; i < 8; ++i) buf[i] = *reinterpret_cast<const float4*>(arow + i * 4);

    for (int h0 = 0; h0 < Hq; h0 += 32) {
        float4 nxt[8];
        const bool more = (h0 + 32) < Hq;
        if (more) {
            #pragma unroll
            for (int i = 0; i < 8; ++i)
                nxt[i] = *reinterpret_cast<const float4*>(arow + h0 + 32 + i * 4);
        }
        #pragma unroll
        for (int i = 0; i < 8; ++i) {
            const float* wb = W + (size_t)(h0 + i * 4) * Tq;   // wave-uniform -> s_load
            #pragma unroll
            for (int u = 0; u < 4; ++u) {
                float av = (u == 0) ? buf[i].x : (u == 1) ? buf[i].y : (u == 2) ? buf[i].z : buf[i].w;
                #pragma unroll
                for (int t = 0; t < 16; ++t)
                    acc[t] = fmaf(av, wb[u * Tq + t], acc[t]);
            }
        }
        if (more) {
            #pragma unroll
            for (int i = 0; i < 8; ++i) buf[i] = nxt[i];
        }
    }
    if (v < Vq) {
        #pragma unroll
        for (int c = 0; c < 4; ++c)
            *reinterpret_cast<float4*>(table + (size_t)v * Tq + c * 4) =
                make_float4(acc[c * 4], acc[c * 4 + 1], acc[c * 4 + 2], acc[c * 4 + 3]);
    }
}

// ---------- K1: fused CRF scans. grid=128, block=64 (1 wave). ----------
__global__ __launch_bounds__(64) void k_scan(const int* __restrict__ src,
                                             const int* __restrict__ label,
                                             const int* __restrict__ pmask,
                                             const float* __restrict__ table,
                                             const float* __restrict__ start_t,
                                             const float* __restrict__ end_t,
                                             const float* __restrict__ trans,
                                             float* __restrict__ nd,
                                             float* __restrict__ out) {
    __shared__ float em[Sq * Tq];
    __shared__ __align__(16) unsigned char hist8[Sq * Tq]; // rows 0..510 + row 511 = identity
    __shared__ int srcl[Sq];
    __shared__ int labl[Sq];
    __shared__ __align__(8) unsigned char predi8[Sq];

    const int lane = threadIdx.x;
    const int b = blockIdx.x & 63;
    const bool vit = blockIdx.x >= 64;

    #pragma unroll
    for (int k = 0; k < 8; ++k) {
        int t = lane + (k << 6);
        srcl[t] = src[b * Sq + t];
        labl[t] = label[b * Sq + t];
    }
    __syncthreads();
    #pragma unroll 4
    for (int k = 0; k < 128; ++k) {
        int idx = lane + (k << 6);
        em[idx] = table[(size_t)srcl[idx >> 4] * Tq + (idx & 15)];
    }
    __syncthreads();

    const int j = lane >> 2;   // target state
    const int g = lane & 3;    // prev-state group

    // ---- probe the fast gather network; fall back to bpermute if semantics differ ----
    const bool swA = (((lane >> 5) ^ (lane >> 1)) & 1) != 0;
    const bool swB = (((lane >> 4) ^ lane) & 1) != 0;
    int k0 = 0, k1 = 1, k2 = 2, k3 = 3;
    bool fastok = false;
#if HAVE_PL
    {
        u32 q0, q1, q2, q3;
        gather4((u32)j, swA, swB, q0, q1, q2, q3);
        bool ok = ((q0 >> 2) == (u32)g) && ((q1 >> 2) == (u32)g) &&
                  ((q2 >> 2) == (u32)g) && ((q3 >> 2) == (u32)g);
        u32 cov = (1u << (q0 & 3)) | (1u << (q1 & 3)) | (1u << (q2 & 3)) | (1u << (q3 & 3));
        ok = ok && (cov == 15u);
        fastok = (__all(ok ? 1 : 0) != 0);
        if (fastok) { k0 = (int)(q0 & 3); k1 = (int)(q1 & 3); k2 = (int)(q2 & 3); k3 = (int)(q3 & 3); }
    }
#endif
    const int bidx0 = (g << 6), bidx1 = (g << 6) + 16, bidx2 = (g << 6) + 32, bidx3 = (g << 6) + 48;

    if (!vit) {
        // ================= denominator: linear-domain forward =================
        float E0 = __expf(trans[(4 * g + k0) * Tq + j]);
        float E1 = __expf(trans[(4 * g + k1) * Tq + j]);
        float E2 = __expf(trans[(4 * g + k2) * Tq + j]);
        float E3 = __expf(trans[(4 * g + k3) * Tq + j]);
        float p = __expf(start_t[j] + em[j]);
        float emA = em[Tq + j], emB = em[2 * Tq + j], emC = em[3 * Tq + j];
#if HAVE_PL
        if (fastok) {
            for (int t = 1; t < Sq; ++t) {
                float FF = __expf(emA) * 0.0625f;
                emA = emB; emB = emC;
                int tn = t + 3; if (tn > Sq - 1) tn = Sq - 1;
                emC = em[tn * Tq + j];
                u32 qa, qb, qc, qd;
                gather4(__float_as_uint(p), swA, swB, qa, qb, qc, qd);
                float s = (__uint_as_float(qa) * E0 + __uint_as_float(qb) * E1)
                        + (__uint_as_float(qc) * E2 + __uint_as_float(qd) * E3);
                s += dpp_f<QX1>(s);
                s += dpp_f<QX2>(s);
                p = s * FF;
            }
        } else
#endif
        {
            for (int t = 1; t < Sq; ++t) {
                float FF = __expf(emA) * 0.0625f;
                emA = emB; emB = emC;
                int tn = t + 3; if (tn > Sq - 1) tn = Sq - 1;
                emC = em[tn * Tq + j];
                float p0 = bperm_f(p, bidx0);
                float p1 = bperm_f(p, bidx1);
                float p2 = bperm_f(p, bidx2);
                float p3 = bperm_f(p, bidx3);
                float s = (p0 * E0 + p1 * E1) + (p2 * E2 + p3 * E3);
                s += dpp_f<QX1>(s);
                s += dpp_f<QX2>(s);
                p = s * FF;
            }
        }
        float val = p * __expf(end_t[j]);
        #pragma unroll
        for (int off = 1; off < 64; off <<= 1) val += __shfl_xor(val, off);
        float den = (float)(511.0 * 2.7725887222397811) + __logf(val * 0.25f);

        // ================= numerator =================
        float numv = 0.0f;
        int sl = 0;
        #pragma unroll
        for (int k = 0; k < 8; ++k) {
            int t = lane + (k << 6);
            int tag = labl[t];
            int m = pmask[b * Sq + t];
            sl += m;
            if (t == 0) {
                numv += start_t[tag] + em[tag];
            } else {
                int tp = labl[t - 1];
                numv += (float)m * (trans[tp * Tq + tag] + em[t * Tq + tag]);
            }
        }
        #pragma unroll
        for (int off = 1; off < 64; off <<= 1) {
            numv += __shfl_xor(numv, off);
            sl += __shfl_xor(sl, off);
        }
        if (lane == 0) {
            int last = labl[sl - 1];
            nd[b] = (numv + end_t[last]) - den;
        }
    } else {
        // ================= viterbi forward =================
        float T0 = trans[(4 * g + k0) * Tq + j];
        float T1 = trans[(4 * g + k1) * Tq + j];
        float T2 = trans[(4 * g + k2) * Tq + j];
        float T3 = trans[(4 * g + k3) * Tq + j];
        const int i0 = 4 * g + k0, i1 = 4 * g + k1, i2 = 4 * g + k2, i3 = 4 * g + k3;
        float sc = start_t[j] + em[j];
        float emA = em[Tq + j], emB = em[2 * Tq + j], emC = em[3 * Tq + j];
#if HAVE_PL
        if (fastok) {
            for (int t = 1; t < Sq; ++t) {
                float emv = emA;
                emA = emB; emB = emC;
                int tn = t + 3; if (tn > Sq - 1) tn = Sq - 1;
                emC = em[tn * Tq + j];
                u32 qa, qb, qc, qd;
                gather4(__float_as_uint(sc), swA, swB, qa, qb, qc, qd);
                float v0 = __uint_as_float(qa) + T0;
                float v1 = __uint_as_float(qb) + T1;
                float v2 = __uint_as_float(qc) + T2;
                float v3 = __uint_as_float(qd) + T3;
                float ml = fmaxf(fmaxf(v0, v1), fmaxf(v2, v3));
                float m1 = fmaxf(ml, dpp_f<QX1>(ml));
                float mv = fmaxf(m1, dpp_f<QX2>(m1));
                sc = mv + emv;
                int c0 = (v0 == mv) ? i0 : 99;
                int c1 = (v1 == mv) ? i1 : 99;
                int c2 = (v2 == mv) ? i2 : 99;
                int c3 = (v3 == mv) ? i3 : 99;
                int li = min(min(c0, c1), min(c2, c3));
                li = min(li, dpp_i<QX1>(li));
                li = min(li, dpp_i<QX2>(li));
                if (g == 0) hist8[(t - 1) * Tq + j] = (unsigned char)li;
            }
        } else
#endif
        {
            for (int t = 1; t < Sq; ++t) {
                float emv = emA;
                emA = emB; emB = emC;
                int tn = t + 3; if (tn > Sq - 1) tn = Sq - 1;
                emC = em[tn * Tq + j];
                float v0 = bperm_f(sc, bidx0) + T0;
                float v1 = bperm_f(sc, bidx1) + T1;
                float v2 = bperm_f(sc, bidx2) + T2;
                float v3 = bperm_f(sc, bidx3) + T3;
                float ml = fmaxf(fmaxf(v0, v1), fmaxf(v2, v3));
                float m1 = fmaxf(ml, dpp_f<QX1>(ml));
                float mv = fmaxf(m1, dpp_f<QX2>(m1));
                sc = mv + emv;
                int c0 = (v0 == mv) ? i0 : 99;
                int c1 = (v1 == mv) ? i1 : 99;
                int c2 = (v2 == mv) ? i2 : 99;
                int c3 = (v3 == mv) ? i3 : 99;
                int li = min(min(c0, c1), min(c2, c3));
                li = min(li, dpp_i<QX1>(li));
                li = min(li, dpp_i<QX2>(li));
                if (g == 0) hist8[(t - 1) * Tq + j] = (unsigned char)li;
            }
        }
        // final argmax over states (ties -> lowest index)
        float fv = sc + end_t[j];
        int fi = j;
        #pragma unroll
        for (int off = 4; off < 64; off <<= 1) {
            float ov = __shfl_xor(fv, off);
            int oi = __shfl_xor(fi, off);
            bool take = (ov > fv) || (ov == fv && oi < fi);
            fv = take ? ov : fv;
            fi = take ? oi : fi;
        }
        // identity function as row 511 -> uniform 8-row chunks
        if (lane < 16) hist8[511 * Tq + lane] = (unsigned char)lane;
        __syncthreads();

        // ===== backtrack via exact function-composition scan =====
        // phase 1: lane c composes its 8 rows (nibble-packed functions)
        u64 rp[8];
        #pragma unroll
        for (int k = 0; k < 8; ++k) {
            uint4 rw = *reinterpret_cast<const uint4*>(&hist8[(lane * 8 + k) * Tq]);
            u32 lo = packnib(rw.x) | (packnib(rw.y) << 16);
            u32 hi = packnib(rw.z) | (packnib(rw.w) << 16);
            rp[k] = (u64)lo | ((u64)hi << 32);
        }
        u64 F = rp[7];
        #pragma unroll
        for (int k = 6; k >= 0; --k) {
            u64 nf = 0;
            #pragma unroll
            for (int e = 0; e < 16; ++e) {
                u32 s = (u32)(F >> (e * 4)) & 15u;
                nf |= ((u64)nib64(rp[k], s)) << (e * 4);
            }
            F = nf;
        }
        u32 Flo = (u32)F, Fhi = (u32)(F >> 32);

        // phase 2: sequential scalar scan over 64 chunk functions
        u32 pk[8] = {0, 0, 0, 0, 0, 0, 0, 0};
        u32 E = (u32)fi;
        #pragma unroll 64
        for (int c = 63; c >= 0; --c) {
            u64 Fc = ((u64)(u32)__builtin_amdgcn_readlane((int)Fhi, c) << 32)
                   | (u64)(u32)__builtin_amdgcn_readlane((int)Flo, c);
            pk[c >> 3] |= E << ((c & 7) * 4);   // record entry state E_c
            E = nib64(Fc, E);
        }

        // phase 3: parallel expansion; lane c emits predi[8c..8c+7]
        u32 a0 = (lane & 8) ? pk[1] : pk[0];
        u32 a1 = (lane & 8) ? pk[3] : pk[2];
        u32 a2 = (lane & 8) ? pk[5] : pk[4];
        u32 a3 = (lane & 8) ? pk[7] : pk[6];
        u32 b0 = (lane & 16) ? a1 : a0;
        u32 b1 = (lane & 16) ? a3 : a2;
        u32 c0s = (lane & 32) ? b1 : b0;
        u32 cur = (c0s >> ((lane & 7) * 4)) & 15u;
        u32 w0 = 0, w1 = 0;
        #pragma unroll
        for (int k = 7; k >= 0; --k) {
            cur = nib64(rp[k], cur);
            if (k >= 4) w1 |= cur << ((k - 4) * 8);
            else        w0 |= cur << (k * 8);
        }
        *reinterpret_cast<uint2*>(&predi8[lane * 8]) = make_uint2(w0, w1);
        __syncthreads();

        // ================= outputs =================
        int cnt = 0;
        #pragma unroll
        for (int k = 0; k < 8; ++k) {
            int s_ = lane + (k << 6);
            int lab = labl[s_];
            int pr = (int)predi8[s_];
            int mpr = lab > 0 ? pr : 0;
            out[2 + b * Sq + s_] = (float)mpr;
            out[2 + Bq * Sq + b * Sq + s_] = (float)lab;
            cnt += (mpr == lab) ? 1 : 0;
        }
        #pragma unroll
        for (int off = 1; off < 64; off <<= 1) cnt += __shfl_xor(cnt, off);
        if (lane == 0) atomicAdd(out + 1, (float)cnt);
    }
}

// ---------- K2: loss = -(sum_b nd[b]) / B ----------
__global__ __launch_bounds__(64) void k_final(const float* __restrict__ nd,
                                              float* __restrict__ out) {
    float v = nd[threadIdx.x];
    #pragma unroll
    for (int off = 1; off < 64; off <<= 1) v += __shfl_xor(v, off);
    if (threadIdx.x == 0) out[0] = -v * (1.0f / (float)Bq);
}

extern "C" void kernel_launch(void* const* d_in, const int* in_sizes, int n_in,
                              void* d_out, int out_size, void* d_ws, size_t ws_size,
                              hipStream_t stream) {
    const int*   src   = (const int*)d_in[0];
    const int*   label = (const int*)d_in[1];
    const int*   pmask = (const int*)d_in[2];
    const float* emb   = (const float*)d_in[3];
    const float* W     = (const float*)d_in[4];
    const float* bias  = (const float*)d_in[5];
    const float* st    = (const float*)d_in[6];
    const float* en    = (const float*)d_in[7];
    const float* tr    = (const float*)d_in[8];
    float* out = (float*)d_out;

    float* table = (float*)d_ws;              // V*T floats = 1.95 MB
    float* nd    = table + (size_t)Vq * Tq;   // 64 floats

    const int nblk = (Vq + 63) / 64;          // 477
    k_table<<<nblk, 64, 0, stream>>>(emb, W, bias, table, out);
    k_scan<<<128, 64, 0, stream>>>(src, label, pmask, table, st, en, tr, nd, out);
    k_final<<<1, 64, 0, stream>>>(nd, out);
}